// Round 24
// baseline (144.711 us; speedup 1.0000x reference)
//
#include <hip/hip_runtime.h>
#include <hip/hip_bf16.h>

// Problem constants: B=16, N=16384, D=256, grid 128x128, K=3 depthwise, GELU.
// coords = per-batch permutation of all cells -> collision-free, min=(0,0).
//
// R20 = R19's 2-column-phase design, bug-fixed (R19 failed because halo col
// 17 was never loaded: U-load guard was p<6 instead of p<7). Phase p
// computes tile cols {2p,2p+1} from window {P,Q,R,S}=halo{2p..2p+3};
// prefetch T=2p+4 before COMPCOL1, U=2p+5 between COMPCOLs (consumed next
// phase -> ~full phase of latency cover, lower peak liveness).
// __launch_bounds__(256,3) (VGPR cap 170) prevents the 84-VGPR
// clamp-and-resink seen in R13/R14/R18. Keeps: nt stores (R16 A/B),
// lane-packed readlane indices (R17, LDS=0), sched_barrier pinning (R14).
#define BB 16
#define NN 16384
#define GW 128
#define TS 16
#define HS 18

typedef float f32x4 __attribute__((ext_vector_type(4)));

// ---------------------------------------------------------------------------
// Kernel 1: inverse permutation + zero-row init
// ---------------------------------------------------------------------------
__global__ __launch_bounds__(256) void build_inv_kernel(
    const int* __restrict__ coords, int* __restrict__ inv,
    float* __restrict__ zrow) {
  int i = blockIdx.x * blockDim.x + threadIdx.x;   // 0 .. B*N-1
  int b = i >> 14;
  int gx = coords[2 * (size_t)i];
  int gy = coords[2 * (size_t)i + 1];
  inv[(b << 14) + (gy << 7) + gx] = i & (NN - 1);
  if (blockIdx.x == 0) zrow[threadIdx.x] = 0.0f;   // 256 floats = 1 row
}

__device__ __forceinline__ float gelu_fast(float a) {
  // gelu_tanh(a) = a * sigmoid(1.5957691216*(a + 0.044715*a^3))
  const float s = a * a;
  const float t = fmaf(0.044715f * a, s, a);
  const float e = __builtin_amdgcn_exp2f(t * -2.3022083f);
  return a * __builtin_amdgcn_rcpf(1.0f + e);
}

// halo index k = r*18 + j  (r: wave-relative row 0..5, j: halo col 0..17)
#define HIDX(k) \
  __builtin_amdgcn_readlane(((k) < 64 ? vIdx0 : vIdx1), (k) & 63)

// load halo column j (6 stacked rows) for this lane's 4 channels
#define LCOL(j, col)                                                      \
  _Pragma("unroll") for (int r6 = 0; r6 < 6; ++r6) {                     \
    const int n_ = HIDX(r6 * HS + (j));                                  \
    const float* p_ = (n_ >= 0) ? xb + ((size_t)n_ << 8) : zrow;         \
    col[r6] = *(const f32x4*)(p_ + c4);                                  \
  }

// compute one output column (tile rows r0..r0+3); center column = w1,
// output halo col = jc (center's halo col)
#define COMPCOL(w0, w1, w2, jc)                                           \
  _Pragma("unroll") for (int rr = 0; rr < 4; ++rr) {                      \
    f32x4 a = bq;                                                         \
    a += wq[0] * w0[rr];                                                  \
    a += wq[1] * w1[rr];                                                  \
    a += wq[2] * w2[rr];                                                  \
    a += wq[3] * w0[rr + 1];                                              \
    a += wq[4] * w1[rr + 1];                                              \
    a += wq[5] * w2[rr + 1];                                              \
    a += wq[6] * w0[rr + 2];                                              \
    a += wq[7] * w1[rr + 2];                                              \
    a += wq[8] * w2[rr + 2];                                              \
    f32x4 res;                                                            \
    _Pragma("unroll") for (int cc = 0; cc < 4; ++cc)                      \
        res[cc] = w1[rr + 1][cc] + gelu_fast(a[cc]);                      \
    const int n = HIDX((rr + 1) * HS + (jc));                             \
    __builtin_nontemporal_store(res, (f32x4*)(ob + ((size_t)n << 8) + c4)); \
  }

// ---------------------------------------------------------------------------
// Kernel 2: 16x16 tile; wave w -> rows 4w..4w+3; lane -> 4 channels (f32x4).
// 8 phases x 2 output columns.
// ---------------------------------------------------------------------------
__global__ __launch_bounds__(256, 3) void mixer_kernel(
    const float* __restrict__ x, const float* __restrict__ cw,
    const float* __restrict__ cb, const int* __restrict__ inv,
    const float* __restrict__ zrow, float* __restrict__ out) {
  const int id = blockIdx.x;               // 1024 blocks
  const int rem = id >> 3;
  const int b = ((id & 7) << 1) + (rem >> 6);   // XCD-swizzled batch
  const int tile = rem & 63;
  const int gy0 = (tile >> 3) * TS;
  const int gx0 = (tile & 7) * TS;

  const int tid = threadIdx.x;
  const int lane = tid & 63;
  const int wv = tid >> 6;
  const int c4 = lane << 2;                // first channel of this lane
  const int r0 = wv << 2;                  // wave's halo row base

  // ---- lane-packed halo indices for THIS wave (k = r*18 + j) ----
  const int* __restrict__ invb = inv + (b << 14);
  int vIdx0, vIdx1;
  {
    const unsigned k0 = lane;                    // 0..63
    const int r_0 = k0 / HS, j_0 = k0 - r_0 * HS;
    const int gy_0 = gy0 - 1 + r0 + r_0, gx_0 = gx0 - 1 + j_0;
    vIdx0 = ((unsigned)gy_0 < (unsigned)GW && (unsigned)gx_0 < (unsigned)GW)
                ? invb[(gy_0 << 7) + gx_0] : -1;
    const unsigned k1 = 64 + lane;               // 64..127 (valid < 108)
    const int r_1 = k1 / HS, j_1 = k1 - r_1 * HS;
    const int gy_1 = gy0 - 1 + r0 + r_1, gx_1 = gx0 - 1 + j_1;
    vIdx1 = (k1 < 6 * HS && (unsigned)gy_1 < (unsigned)GW &&
             (unsigned)gx_1 < (unsigned)GW)
                ? invb[(gy_1 << 7) + gx_1] : -1;
  }

  // per-lane weights/bias for channels c4..c4+3
  f32x4 wq[9], bq;
#pragma unroll
  for (int cc = 0; cc < 4; ++cc) {
    bq[cc] = cb[c4 + cc];
#pragma unroll
    for (int j = 0; j < 9; ++j) wq[j][cc] = cw[(c4 + cc) * 9 + j];
  }

  const float* __restrict__ xb = x + ((size_t)b << 22);
  float* __restrict__ ob = out + ((size_t)b << 22);

  // window {P,Q,R,S} = halo {2p..2p+3}; prefetch T=2p+4, U=2p+5
  f32x4 cP[6], cQ[6], cR[6], cS[6], cT[6], cU[6];
  LCOL(0, cP)
  LCOL(1, cQ)
  LCOL(2, cR)
  LCOL(3, cS)
#pragma unroll
  for (int p = 0; p < 8; ++p) {
    // A) prefetch halo col 2p+4 -- pinned before first compute
    if (p < 7) { LCOL(2 * p + 4, cT) }
    __builtin_amdgcn_sched_barrier(0);

    // B1) tile col 2p: needs halo {2p,2p+1,2p+2} = P,Q,R
    COMPCOL(cP, cQ, cR, 2 * p + 1)

    // A2) prefetch halo col 2p+5 (consumed next phase as S) -- pinned
    if (p < 7) { LCOL(2 * p + 5, cU) }
    __builtin_amdgcn_sched_barrier(0);

    // B2) tile col 2p+1: needs halo {2p+1,2p+2,2p+3} = Q,R,S
    COMPCOL(cQ, cR, cS, 2 * p + 2)

    // C) rotate by 2 columns: {P,Q,R,S} <- {R,S,T,U}
    if (p < 7) {
#pragma unroll
      for (int r6 = 0; r6 < 6; ++r6) {
        cP[r6] = cR[r6];
        cQ[r6] = cS[r6];
        cR[r6] = cT[r6];
        cS[r6] = cU[r6];
      }
    }
  }
}

// ---------------------------------------------------------------------------
extern "C" void kernel_launch(void* const* d_in, const int* in_sizes, int n_in,
                              void* d_out, int out_size, void* d_ws,
                              size_t ws_size, hipStream_t stream) {
  const float* x = (const float*)d_in[0];
  const int* coords = (const int*)d_in[1];
  const float* cw = (const float*)d_in[2];
  const float* cb = (const float*)d_in[3];
  float* out = (float*)d_out;
  int* inv = (int*)d_ws;                        // B*N ints = 1 MiB
  float* zrow = (float*)d_ws + (size_t)BB * NN; // 256 floats after inv

  {
    dim3 grid((BB * NN) / 256), block(256);
    build_inv_kernel<<<grid, block, 0, stream>>>(coords, inv, zrow);
  }
  {
    dim3 grid(BB * (GW / TS) * (GW / TS)), block(256);   // 1024 blocks
    mixer_kernel<<<grid, block, 0, stream>>>(x, cw, cb, inv, zrow, out);
  }
}

// Round 25
// 106.050 us; speedup vs baseline: 1.3646x; 1.3646x over previous
//
#include <hip/hip_runtime.h>
#include <hip/hip_bf16.h>

// Problem constants: B=16, N=16384, D=256, grid 128x128, K=3 depthwise, GELU.
// coords = per-batch permutation of all cells -> collision-free, min=(0,0).
//
// R25: global_load_lds pipeline. Five rounds (R13/14/18/20) proved the
// register allocator re-sinks VGPR-resident prefetches (VGPR pinned at ~84).
// Fix: in-flight data lives in LDS via __builtin_amdgcn_global_load_lds
// (no VGPR liveness to fight), waits counted manually (asm vmcnt(N), never 0
// in the loop; m201 pattern). Per-wave PRIVATE 3-slot column ring (6 rows x
// 1KB per slot; 72KB/block -> 2 blocks/CU -> 256-VGPR tier free). No
// __syncthreads in the loop (waves own their slots). Per phase: issue col
// p+2 -> vmcnt(10) (retire only col p+1's 6 loads; 4 stores + 6 new loads
// stay in flight) -> ds_read col p+1 -> compute col p. sched_barrier(0)
// fences issue/wait/read (rule #18). Keeps: nt stores, readlane indices,
// gelu_fast, XCD swizzle.
#define BB 16
#define NN 16384
#define GW 128
#define TS 16
#define HS 18

typedef float f32x4 __attribute__((ext_vector_type(4)));
typedef const __attribute__((address_space(1))) unsigned int guint_t;
typedef __attribute__((address_space(3))) unsigned int luint_t;

// ---------------------------------------------------------------------------
// Kernel 1: inverse permutation + zero-row init
// ---------------------------------------------------------------------------
__global__ __launch_bounds__(256) void build_inv_kernel(
    const int* __restrict__ coords, int* __restrict__ inv,
    float* __restrict__ zrow) {
  int i = blockIdx.x * blockDim.x + threadIdx.x;   // 0 .. B*N-1
  int b = i >> 14;
  int gx = coords[2 * (size_t)i];
  int gy = coords[2 * (size_t)i + 1];
  inv[(b << 14) + (gy << 7) + gx] = i & (NN - 1);
  if (blockIdx.x == 0) zrow[threadIdx.x] = 0.0f;   // 256 floats = 1 row
}

__device__ __forceinline__ float gelu_fast(float a) {
  // gelu_tanh(a) = a * sigmoid(1.5957691216*(a + 0.044715*a^3))
  const float s = a * a;
  const float t = fmaf(0.044715f * a, s, a);
  const float e = __builtin_amdgcn_exp2f(t * -2.3022083f);
  return a * __builtin_amdgcn_rcpf(1.0f + e);
}

// halo index k = r*18 + j  (r: wave-relative row 0..5, j: halo col 0..17)
#define HIDX(k) \
  __builtin_amdgcn_readlane(((k) < 64 ? vIdx0 : vIdx1), (k) & 63)

// issue 6 global_load_lds: halo column j -> ring slot (1KB per row,
// HW writes lds_base + lane*16, exactly our layout)
#define ISSUECOL(j, slot)                                                 \
  _Pragma("unroll") for (int r6 = 0; r6 < 6; ++r6) {                      \
    const int n_ = HIDX(r6 * HS + (j));                                   \
    const float* g_ = (n_ >= 0) ? xb + ((size_t)n_ << 8) : zrow;          \
    __builtin_amdgcn_global_load_lds(                                     \
        (guint_t*)(g_ + c4),                                              \
        (luint_t*)(ringw + (((slot) * 6 + r6) << 8)), 16, 0, 0);          \
  }

// ds_read one staged column into registers (lane reads its own 16B)
#define READCOL(slot, col)                                                \
  _Pragma("unroll") for (int r6 = 0; r6 < 6; ++r6)                        \
    col[r6] = *(const f32x4*)(ringw + (((slot) * 6 + r6) << 8) + c4);

// compute one output column (tile rows r0..r0+3); center column = w1,
// output halo col = jc
#define COMPCOL(w0, w1, w2, jc)                                           \
  _Pragma("unroll") for (int rr = 0; rr < 4; ++rr) {                      \
    f32x4 a = bq;                                                         \
    a += wq[0] * w0[rr];                                                  \
    a += wq[1] * w1[rr];                                                  \
    a += wq[2] * w2[rr];                                                  \
    a += wq[3] * w0[rr + 1];                                              \
    a += wq[4] * w1[rr + 1];                                              \
    a += wq[5] * w2[rr + 1];                                              \
    a += wq[6] * w0[rr + 2];                                              \
    a += wq[7] * w1[rr + 2];                                              \
    a += wq[8] * w2[rr + 2];                                              \
    f32x4 res;                                                            \
    _Pragma("unroll") for (int cc = 0; cc < 4; ++cc)                      \
        res[cc] = w1[rr + 1][cc] + gelu_fast(a[cc]);                      \
    const int n = HIDX((rr + 1) * HS + (jc));                             \
    __builtin_nontemporal_store(res, (f32x4*)(ob + ((size_t)n << 8) + c4)); \
  }

// ---------------------------------------------------------------------------
// Kernel 2: 16x16 tile; wave w -> rows 4w..4w+3; lane -> 4 channels (f32x4).
// Per-wave private 3-slot LDS column ring, counted-vmcnt pipeline.
// ---------------------------------------------------------------------------
__global__ __launch_bounds__(256, 2) void mixer_kernel(
    const float* __restrict__ x, const float* __restrict__ cw,
    const float* __restrict__ cb, const int* __restrict__ inv,
    const float* __restrict__ zrow, float* __restrict__ out) {
  __shared__ float ring[4 * 3 * 6 * 256];  // 72 KB: 4 waves x 3 slots x 6 rows

  const int id = blockIdx.x;               // 1024 blocks
  const int rem = id >> 3;
  const int b = ((id & 7) << 1) + (rem >> 6);   // XCD-swizzled batch
  const int tile = rem & 63;
  const int gy0 = (tile >> 3) * TS;
  const int gx0 = (tile & 7) * TS;

  const int tid = threadIdx.x;
  const int lane = tid & 63;
  const int wv = tid >> 6;
  const int c4 = lane << 2;                // first channel of this lane
  const int r0 = wv << 2;                  // wave's halo row base
  float* const ringw = &ring[wv * (3 * 6 * 256)];  // wave-private ring

  // ---- lane-packed halo indices for THIS wave (k = r*18 + j) ----
  const int* __restrict__ invb = inv + (b << 14);
  int vIdx0, vIdx1;
  {
    const unsigned k0 = lane;                    // 0..63
    const int r_0 = k0 / HS, j_0 = k0 - r_0 * HS;
    const int gy_0 = gy0 - 1 + r0 + r_0, gx_0 = gx0 - 1 + j_0;
    vIdx0 = ((unsigned)gy_0 < (unsigned)GW && (unsigned)gx_0 < (unsigned)GW)
                ? invb[(gy_0 << 7) + gx_0] : -1;
    const unsigned k1 = 64 + lane;               // 64..127 (valid < 108)
    const int r_1 = k1 / HS, j_1 = k1 - r_1 * HS;
    const int gy_1 = gy0 - 1 + r0 + r_1, gx_1 = gx0 - 1 + j_1;
    vIdx1 = (k1 < 6 * HS && (unsigned)gy_1 < (unsigned)GW &&
             (unsigned)gx_1 < (unsigned)GW)
                ? invb[(gy_1 << 7) + gx_1] : -1;
  }

  // per-lane weights/bias for channels c4..c4+3
  f32x4 wq[9], bq;
#pragma unroll
  for (int cc = 0; cc < 4; ++cc) {
    bq[cc] = cb[c4 + cc];
#pragma unroll
    for (int j = 0; j < 9; ++j) wq[j][cc] = cw[(c4 + cc) * 9 + j];
  }

  const float* __restrict__ xb = x + ((size_t)b << 22);
  float* __restrict__ ob = out + ((size_t)b << 22);

  // ---- prologue: stage halo cols 0,1,2 into slots 0,1,2 ----
  ISSUECOL(0, 0)
  ISSUECOL(1, 1)
  ISSUECOL(2, 2)
  __builtin_amdgcn_sched_barrier(0);
  asm volatile("s_waitcnt vmcnt(6)" ::: "memory");   // cols 0,1 landed
  __builtin_amdgcn_sched_barrier(0);

  f32x4 cA[6], cB[6], cC[6];
  READCOL(0, cA)
  READCOL(1, cB)

  // ---- 16 phases: phase p computes output halo col p (tile col p-1) ----
#pragma unroll
  for (int p = 1; p <= 16; ++p) {
    // A) issue next column's 6 loads into slot (p+2)%3 (last read 2 phases
    //    ago -> safe). Counted, never drained to 0.
    if (p <= 15) { ISSUECOL(p + 2, (p + 2) % 3) }
    __builtin_amdgcn_sched_barrier(0);
    // B) retire exactly col p+1's loads (oldest 6). Outstanding after wait:
    //    p==1: col3(6). p in 2..15: stores(4)+col p+2(6)=10. p==16: stores(4).
    if (p == 1) {
      asm volatile("s_waitcnt vmcnt(6)" ::: "memory");
    } else if (p <= 15) {
      asm volatile("s_waitcnt vmcnt(10)" ::: "memory");
    } else {
      asm volatile("s_waitcnt vmcnt(4)" ::: "memory");
    }
    __builtin_amdgcn_sched_barrier(0);
    // C) read col p+1 from its slot; compute col p; rotate window
    READCOL((p + 1) % 3, cC)
    COMPCOL(cA, cB, cC, p)
#pragma unroll
    for (int r6 = 0; r6 < 6; ++r6) {
      cA[r6] = cB[r6];
      cB[r6] = cC[r6];
    }
  }
}

// ---------------------------------------------------------------------------
extern "C" void kernel_launch(void* const* d_in, const int* in_sizes, int n_in,
                              void* d_out, int out_size, void* d_ws,
                              size_t ws_size, hipStream_t stream) {
  const float* x = (const float*)d_in[0];
  const int* coords = (const int*)d_in[1];
  const float* cw = (const float*)d_in[2];
  const float* cb = (const float*)d_in[3];
  float* out = (float*)d_out;
  int* inv = (int*)d_ws;                        // B*N ints = 1 MiB
  float* zrow = (float*)d_ws + (size_t)BB * NN; // 256 floats after inv

  {
    dim3 grid((BB * NN) / 256), block(256);
    build_inv_kernel<<<grid, block, 0, stream>>>(coords, inv, zrow);
  }
  {
    dim3 grid(BB * (GW / TS) * (GW / TS)), block(256);   // 1024 blocks
    mixer_kernel<<<grid, block, 0, stream>>>(x, cw, cb, inv, zrow, out);
  }
}

// Round 26
// 105.250 us; speedup vs baseline: 1.3749x; 1.0076x over previous
//
#include <hip/hip_runtime.h>
#include <hip/hip_bf16.h>

// Problem constants: B=16, N=16384, D=256, grid 128x128, K=3 depthwise, GELU.
// coords = per-batch permutation of all cells -> collision-free, min=(0,0).
//
// FINAL (revert to R14, best measured: 104.1 us). Roofline rationale:
// five structurally different schedules (reg-prefetch, pinned prefetch,
// LDS ring+barriers, per-wave LDS ring+counted vmcnt, TLP x2/x4) all
// converge at 104-106 us. Traffic is near-minimal (FETCH ~150 MB + WRITE
// 256 MB HBM; 432 KB/block cache-level reads). Per-CU combined memory
// throughput ~12.6 B/cyc/CU exceeds the per-CU streaming ceiling
// (~10.2 B/cyc/CU from the 6.3 TB/s m13 ubench) -> the per-CU vector
// memory path is saturated. VALUBusy 15% is the signature of a saturated
// shared pipe, not hideable latency.
#define BB 16
#define NN 16384
#define GW 128
#define TS 16
#define HS 18

typedef float f32x4 __attribute__((ext_vector_type(4)));

// ---------------------------------------------------------------------------
// Kernel 1: inverse permutation + zero-row init
// ---------------------------------------------------------------------------
__global__ __launch_bounds__(256) void build_inv_kernel(
    const int* __restrict__ coords, int* __restrict__ inv,
    float* __restrict__ zrow) {
  int i = blockIdx.x * blockDim.x + threadIdx.x;   // 0 .. B*N-1
  int b = i >> 14;
  int gx = coords[2 * (size_t)i];
  int gy = coords[2 * (size_t)i + 1];
  inv[(b << 14) + (gy << 7) + gx] = i & (NN - 1);
  if (blockIdx.x == 0) zrow[threadIdx.x] = 0.0f;   // 256 floats = 1 row
}

__device__ __forceinline__ float gelu_fast(float a) {
  // gelu_tanh(a) = a * sigmoid(1.5957691216*(a + 0.044715*a^3))
  const float s = a * a;
  const float t = fmaf(0.044715f * a, s, a);
  const float e = __builtin_amdgcn_exp2f(t * -2.3022083f);
  return a * __builtin_amdgcn_rcpf(1.0f + e);
}

// load halo column j (6 stacked rows r0..r0+5) for this lane's 4 channels
#define LCOL(j, col)                                                      \
  _Pragma("unroll") for (int r6 = 0; r6 < 6; ++r6) {                      \
    const int n_ = __builtin_amdgcn_readfirstlane(s_inv[r0 + r6][j]);     \
    const float* p_ = (n_ >= 0) ? xb + ((size_t)n_ << 8) : zrow;          \
    col[r6] = *(const f32x4*)(p_ + c4);                                   \
  }

// ---------------------------------------------------------------------------
// Kernel 2: 16x16 tile; wave w -> rows 4w..4w+3; lane -> 4 channels (f32x4).
// ---------------------------------------------------------------------------
__global__ __launch_bounds__(256) void mixer_kernel(
    const float* __restrict__ x, const float* __restrict__ cw,
    const float* __restrict__ cb, const int* __restrict__ inv,
    const float* __restrict__ zrow, float* __restrict__ out) {
  __shared__ int s_inv[HS][HS];

  const int id = blockIdx.x;               // 1024 blocks
  const int rem = id >> 3;
  const int b = ((id & 7) << 1) + (rem >> 6);   // XCD-swizzled batch
  const int tile = rem & 63;
  const int gy0 = (tile >> 3) * TS;
  const int gx0 = (tile & 7) * TS;

  const int tid = threadIdx.x;
  const int lane = tid & 63;
  const int wv = tid >> 6;
  const int c4 = lane << 2;                // first channel of this lane

  for (int t = tid; t < HS * HS; t += 256) {
    const int wy = t / HS, wx = t - wy * HS;
    const int gy = gy0 - 1 + wy, gx = gx0 - 1 + wx;
    int nv = -1;
    if ((unsigned)gy < (unsigned)GW && (unsigned)gx < (unsigned)GW)
      nv = inv[(b << 14) + (gy << 7) + gx];
    s_inv[wy][wx] = nv;
  }

  // per-lane weights/bias for channels c4..c4+3
  f32x4 wq[9], bq;
#pragma unroll
  for (int cc = 0; cc < 4; ++cc) {
    bq[cc] = cb[c4 + cc];
#pragma unroll
    for (int j = 0; j < 9; ++j) wq[j][cc] = cw[(c4 + cc) * 9 + j];
  }
  __syncthreads();

  const float* __restrict__ xb = x + ((size_t)b << 22);
  float* __restrict__ ob = out + ((size_t)b << 22);
  const int r0 = wv << 2;                  // halo row base of this wave

  // sliding 3-column window + 1 prefetch column (all static after unroll)
  f32x4 cA[6], cB[6], cC[6], cD[6];
  LCOL(0, cA)
  LCOL(1, cB)
  LCOL(2, cC)
#pragma unroll
  for (int j = 2; j < HS; ++j) {
    // A) prefetch next column's 6 rows -- pinned before compute
    if (j + 1 < HS) { LCOL(j + 1, cD) }
    __builtin_amdgcn_sched_barrier(0);

    // B) compute outputs: tile rows r0..r0+3, tile column j-2 (halo col j-1)
#pragma unroll
    for (int rr = 0; rr < 4; ++rr) {
      f32x4 a = bq;
      a += wq[0] * cA[rr];
      a += wq[1] * cB[rr];
      a += wq[2] * cC[rr];
      a += wq[3] * cA[rr + 1];
      a += wq[4] * cB[rr + 1];
      a += wq[5] * cC[rr + 1];
      a += wq[6] * cA[rr + 2];
      a += wq[7] * cB[rr + 2];
      a += wq[8] * cC[rr + 2];
      f32x4 res;
#pragma unroll
      for (int cc = 0; cc < 4; ++cc)
        res[cc] = cB[rr + 1][cc] + gelu_fast(a[cc]);
      const int n = __builtin_amdgcn_readfirstlane(s_inv[r0 + rr + 1][j - 1]);
      __builtin_nontemporal_store(res, (f32x4*)(ob + ((size_t)n << 8) + c4));
    }
    // C) rotate window (SSA renames after full unroll)
#pragma unroll
    for (int r6 = 0; r6 < 6; ++r6) {
      cA[r6] = cB[r6];
      cB[r6] = cC[r6];
      cC[r6] = cD[r6];
    }
  }
}

// ---------------------------------------------------------------------------
extern "C" void kernel_launch(void* const* d_in, const int* in_sizes, int n_in,
                              void* d_out, int out_size, void* d_ws,
                              size_t ws_size, hipStream_t stream) {
  const float* x = (const float*)d_in[0];
  const int* coords = (const int*)d_in[1];
  const float* cw = (const float*)d_in[2];
  const float* cb = (const float*)d_in[3];
  float* out = (float*)d_out;
  int* inv = (int*)d_ws;                        // B*N ints = 1 MiB
  float* zrow = (float*)d_ws + (size_t)BB * NN; // 256 floats after inv

  {
    dim3 grid((BB * NN) / 256), block(256);
    build_inv_kernel<<<grid, block, 0, stream>>>(coords, inv, zrow);
  }
  {
    dim3 grid(BB * (GW / TS) * (GW / TS)), block(256);   // 1024 blocks
    mixer_kernel<<<grid, block, 0, stream>>>(x, cw, cb, inv, zrow, out);
  }
}